// Round 1
// baseline (3091.742 us; speedup 1.0000x reference)
//
#include <hip/hip_runtime.h>
#include <hip/hip_bf16.h>
#include <math.h>

#define DHID 128

__device__ __forceinline__ void atomAddF(float* p, float v) {
    __hip_atomic_fetch_add(p, v, __ATOMIC_RELAXED, __HIP_MEMORY_SCOPE_AGENT);
}

// ---------------- degree kernels ----------------
__global__ void deg_init(float* deg, int N) {
    int i = blockIdx.x * 256 + threadIdx.x;
    if (i < N) deg[i] = 1.0f;   // self-loop
}

__global__ void deg_accum(const int* __restrict__ dst, float* __restrict__ deg, int E) {
    int e = blockIdx.x * 256 + threadIdx.x;
    if (e < E) atomAddF(&deg[dst[e]], 1.0f);
}

__global__ void deg_rsqrt(float* deg, int N) {
    int i = blockIdx.x * 256 + threadIdx.x;
    if (i < N) deg[i] = rsqrtf(deg[i]);
}

// ---------------- GEMM: Y[N,128] = (relu?)X[N,128] @ W[128,128] ----------------
// block: 256 threads, 32 rows per block; W + X tile in LDS; 4x4 per-thread tile.
__global__ __launch_bounds__(256) void gemm128(const float* __restrict__ X,
                                               const float* __restrict__ W,
                                               float* __restrict__ Y,
                                               int N, int relu_in) {
    __shared__ float Wl[128 * 128];
    __shared__ float Xl[32 * 128];
    const int tid = threadIdx.x;

    {
        const float4* W4 = (const float4*)W;
        float4* Wl4 = (float4*)Wl;
#pragma unroll
        for (int i = 0; i < 16; i++) Wl4[tid + i * 256] = W4[tid + i * 256];
    }
    const int row0 = blockIdx.x * 32;
    {
        const float4* X4 = (const float4*)X;
        float4* Xl4 = (float4*)Xl;
#pragma unroll
        for (int i = 0; i < 4; i++) {
            int idx = tid + i * 256;          // 0..1023
            int r = idx >> 5;
            float4 v;
            if (row0 + r < N) v = X4[(size_t)(row0 + r) * 32 + (idx & 31)];
            else v = make_float4(0.f, 0.f, 0.f, 0.f);
            if (relu_in) {
                v.x = fmaxf(v.x, 0.f); v.y = fmaxf(v.y, 0.f);
                v.z = fmaxf(v.z, 0.f); v.w = fmaxf(v.w, 0.f);
            }
            Xl4[idx] = v;
        }
    }
    __syncthreads();

    const int cg = tid & 31;   // col group (4 cols)
    const int rg = tid >> 5;   // row group (4 rows)
    float acc[4][4] = {};
    const float4* Wl4 = (const float4*)Wl;
#pragma unroll 4
    for (int k = 0; k < 128; k++) {
        float4 w = Wl4[k * 32 + cg];
        float x0 = Xl[(rg * 4 + 0) * 128 + k];
        float x1 = Xl[(rg * 4 + 1) * 128 + k];
        float x2 = Xl[(rg * 4 + 2) * 128 + k];
        float x3 = Xl[(rg * 4 + 3) * 128 + k];
        acc[0][0] += x0 * w.x; acc[0][1] += x0 * w.y; acc[0][2] += x0 * w.z; acc[0][3] += x0 * w.w;
        acc[1][0] += x1 * w.x; acc[1][1] += x1 * w.y; acc[1][2] += x1 * w.z; acc[1][3] += x1 * w.w;
        acc[2][0] += x2 * w.x; acc[2][1] += x2 * w.y; acc[2][2] += x2 * w.z; acc[2][3] += x2 * w.w;
        acc[3][0] += x3 * w.x; acc[3][1] += x3 * w.y; acc[3][2] += x3 * w.z; acc[3][3] += x3 * w.w;
    }
#pragma unroll
    for (int i = 0; i < 4; i++) {
        int r = row0 + rg * 4 + i;
        if (r < N)
            ((float4*)Y)[(size_t)r * 32 + cg] =
                make_float4(acc[i][0], acc[i][1], acc[i][2], acc[i][3]);
    }
}

// ---------------- B[i,:] = A[i,:]*dinv[i]^2 + b[:] ----------------
__global__ void self_init(const float* __restrict__ A, const float* __restrict__ dinv,
                          const float* __restrict__ b, float* __restrict__ B, int N) {
    int idx = blockIdx.x * 256 + threadIdx.x;   // one float4 each
    if (idx >= N * 32) return;
    int node = idx >> 5;
    int c4 = idx & 31;
    float d = dinv[node];
    float s = d * d;
    float4 a = ((const float4*)A)[idx];
    float4 bb = ((const float4*)b)[c4];
    ((float4*)B)[idx] = make_float4(a.x * s + bb.x, a.y * s + bb.y,
                                    a.z * s + bb.z, a.w * s + bb.w);
}

// ---------------- edge scatter: B[dst] += A[src]*dinv[src]*dinv[dst] ----------------
// 256 threads = 4 edges x 64 lanes; each lane handles 2 consecutive floats.
__global__ __launch_bounds__(256) void scatter_edges(const float* __restrict__ A,
                                                     const float* __restrict__ dinv,
                                                     const int* __restrict__ src,
                                                     const int* __restrict__ dst,
                                                     float* __restrict__ B, int E) {
    int e = blockIdx.x * 4 + (threadIdx.x >> 6);
    if (e >= E) return;
    int lane = threadIdx.x & 63;
    int s = src[e], d = dst[e];
    float norm = dinv[s] * dinv[d];
    float2 a = ((const float2*)(A + (size_t)s * DHID))[lane];
    float* bp = B + (size_t)d * DHID + lane * 2;
    atomAddF(bp, a.x * norm);
    atomAddF(bp + 1, a.y * norm);
}

// ---------------- fused pool + GRU + relu + layernorm + linear ----------------
// one block (128 threads) per graph; batch is sorted -> binary-search the range.
__global__ __launch_bounds__(128) void pool_gru_head(const float* __restrict__ B,
                                                     const int* __restrict__ batch,
                                                     const float* __restrict__ W_ih,
                                                     const float* __restrict__ b_ih,
                                                     const float* __restrict__ b_hh,
                                                     const float* __restrict__ W_lin,
                                                     const float* __restrict__ b_lin,
                                                     float* __restrict__ out,
                                                     int N, int G) {
    __shared__ float Wl[128 * 129];
    __shared__ float gl[128];
    __shared__ float red[2];
    __shared__ int se[2];
    const int t = threadIdx.x;
    const int g = blockIdx.x;

    if (t < 2) {
        int target = g + t, lo = 0, hi = N;
        while (lo < hi) {
            int mid = (lo + hi) >> 1;
            if (batch[mid] < target) lo = mid + 1; else hi = mid;
        }
        se[t] = lo;
    }
    __syncthreads();
    const int s = se[0], e = se[1];

    float sum = 0.f;
    for (int r = s; r < e; r++) sum += B[(size_t)r * DHID + t];
    float gv = sum / fmaxf((float)(e - s), 1.0f);
    gl[t] = gv;

    float dot[3];
#pragma unroll
    for (int ch = 0; ch < 3; ch++) {
        __syncthreads();
        const float* Wc = W_ih + ch * 128 * 128;
        for (int i = t; i < 128 * 128; i += 128)
            Wl[(i >> 7) * 129 + (i & 127)] = Wc[i];
        __syncthreads();
        float acc = 0.f;
        const float* wr = &Wl[t * 129];
#pragma unroll 4
        for (int k = 0; k < 128; k++) acc += gl[k] * wr[k];
        dot[ch] = acc;
    }

    float rg = 1.f / (1.f + expf(-(dot[0] + b_ih[t] + b_hh[t])));
    float zg = 1.f / (1.f + expf(-(dot[1] + b_ih[128 + t] + b_hh[128 + t])));
    float ng = tanhf(dot[2] + b_ih[256 + t] + rg * b_hh[256 + t]);
    float y = fmaxf((1.f - zg) * ng, 0.f);   // h0 = 0, then relu

    auto blockSum = [&](float v) -> float {
#pragma unroll
        for (int o = 1; o < 64; o <<= 1) v += __shfl_xor(v, o);
        __syncthreads();
        if ((t & 63) == 0) red[t >> 6] = v;
        __syncthreads();
        return red[0] + red[1];
    };

    float mu = blockSum(y) * (1.f / 128.f);
    float dy = y - mu;
    float var = blockSum(dy * dy) * (1.f / 128.f);
    float yn = dy * rsqrtf(var + 1e-5f);
    float tot = blockSum(yn * W_lin[t]);
    if (t == 0) out[g] = tot + b_lin[0];
}

extern "C" void kernel_launch(void* const* d_in, const int* in_sizes, int n_in,
                              void* d_out, int out_size, void* d_ws, size_t ws_size,
                              hipStream_t stream) {
    const float* x     = (const float*)d_in[0];
    const int*   ei    = (const int*)d_in[1];
    const int*   batch = (const int*)d_in[2];
    const float* W1    = (const float*)d_in[3];
    const float* b1    = (const float*)d_in[4];
    const float* W2    = (const float*)d_in[5];
    const float* b2    = (const float*)d_in[6];
    const float* W_ih  = (const float*)d_in[7];
    // d_in[8] = W_hh: unused (h0 == 0)
    const float* b_ih  = (const float*)d_in[9];
    const float* b_hh  = (const float*)d_in[10];
    const float* W_lin = (const float*)d_in[11];
    const float* b_lin = (const float*)d_in[12];
    float* out = (float*)d_out;

    const int N = in_sizes[0] / DHID;
    const int E = in_sizes[1] / 2;
    const int G = out_size;
    const int* src = ei;
    const int* dst = ei + E;

    size_t dinv_bytes = (((size_t)N * 4 + 255) / 256) * 256;
    size_t mat_bytes  = (size_t)N * DHID * sizeof(float);

    float* dinv = (float*)d_ws;
    float* A = (float*)((char*)d_ws + dinv_bytes);
    float* B;
    if (ws_size >= dinv_bytes + 2 * mat_bytes) {
        B = A + (size_t)N * DHID;
    } else {
        // fall back to overwriting x (harness restores inputs before every launch;
        // x is fully consumed by the first GEMM before B is written)
        B = (float*)d_in[0];
    }

    dim3 blk(256);
    int nb_n = (N + 255) / 256;
    int nb_e = (E + 255) / 256;
    int nb_g = (N + 31) / 32;
    int nb_s = (N * 32 + 255) / 256;
    int nb_sc = (E + 3) / 4;

    // degrees -> dinv (in place)
    deg_init<<<nb_n, blk, 0, stream>>>(dinv, N);
    deg_accum<<<nb_e, blk, 0, stream>>>(dst, dinv, E);
    deg_rsqrt<<<nb_n, blk, 0, stream>>>(dinv, N);

    // layer 1
    gemm128<<<nb_g, blk, 0, stream>>>(x, W1, A, N, 0);
    self_init<<<nb_s, blk, 0, stream>>>(A, dinv, b1, B, N);
    scatter_edges<<<nb_sc, blk, 0, stream>>>(A, dinv, src, dst, B, E);

    // layer 2 (relu fused into GEMM input read)
    gemm128<<<nb_g, blk, 0, stream>>>(B, W2, A, N, 1);
    self_init<<<nb_s, blk, 0, stream>>>(A, dinv, b2, B, N);
    scatter_edges<<<nb_sc, blk, 0, stream>>>(A, dinv, src, dst, B, E);

    // pool + GRU + relu + layernorm + linear
    pool_gru_head<<<G, dim3(128), 0, stream>>>(B, batch, W_ih, b_ih, b_hh,
                                               W_lin, b_lin, out, N, G);
}

// Round 2
// 816.192 us; speedup vs baseline: 3.7880x; 3.7880x over previous
//
#include <hip/hip_runtime.h>
#include <hip/hip_bf16.h>
#include <math.h>

#define DHID 128

__device__ __forceinline__ void atomAddF(float* p, float v) {
    __hip_atomic_fetch_add(p, v, __ATOMIC_RELAXED, __HIP_MEMORY_SCOPE_AGENT);
}
__device__ __forceinline__ int atomAddI(int* p, int v) {
    return __hip_atomic_fetch_add(p, v, __ATOMIC_RELAXED, __HIP_MEMORY_SCOPE_AGENT);
}

// ---------------- CSR build ----------------
__global__ void zero_counts(int* cnt, int N) {
    int i = blockIdx.x * 256 + threadIdx.x;
    if (i < N) cnt[i] = 0;
}

__global__ void cnt_accum(const int* __restrict__ dst, int* __restrict__ cnt, int E) {
    int e = blockIdx.x * 256 + threadIdx.x;
    if (e < E) atomAddI(&cnt[dst[e]], 1);
}

__global__ void dinv_from_cnt(const int* __restrict__ cnt, float* __restrict__ dinv, int N) {
    int i = blockIdx.x * 256 + threadIdx.x;
    if (i < N) dinv[i] = rsqrtf((float)cnt[i] + 1.0f);
}

// per-block exclusive scan of 256 counts; block total to bsum
__global__ __launch_bounds__(256) void scan_block(const int* __restrict__ cnt,
                                                  int* __restrict__ off,
                                                  int* __restrict__ bsum, int N) {
    __shared__ int sh[256];
    int t = threadIdx.x;
    int i = blockIdx.x * 256 + t;
    int v = (i < N) ? cnt[i] : 0;
    sh[t] = v;
    __syncthreads();
#pragma unroll
    for (int o = 1; o < 256; o <<= 1) {
        int x = (t >= o) ? sh[t - o] : 0;
        __syncthreads();
        sh[t] += x;
        __syncthreads();
    }
    if (i < N) off[i] = sh[t] - v;           // exclusive within block
    if (t == 255) bsum[blockIdx.x] = sh[255];
}

// single-block exclusive scan of bsum[nb] (chunked, carry across chunks)
__global__ __launch_bounds__(512) void scan_bsums(int* bsum, int nb) {
    __shared__ int sh[512];
    int t = threadIdx.x;
    int carry = 0;
    for (int base = 0; base < nb; base += 512) {
        int idx = base + t;
        int v = (idx < nb) ? bsum[idx] : 0;
        sh[t] = v;
        __syncthreads();
#pragma unroll
        for (int o = 1; o < 512; o <<= 1) {
            int x = (t >= o) ? sh[t - o] : 0;
            __syncthreads();
            sh[t] += x;
            __syncthreads();
        }
        if (idx < nb) bsum[idx] = sh[t] - v + carry;
        carry += sh[511];
        __syncthreads();
    }
}

__global__ void add_offsets(int* __restrict__ off, const int* __restrict__ bsum,
                            int* __restrict__ cursor, int N, int E) {
    int i = blockIdx.x * 256 + threadIdx.x;
    if (i < N) {
        int o = off[i] + bsum[i >> 8];
        off[i] = o;
        cursor[i] = o;
    }
    if (i == 0) off[N] = E;
}

__global__ void fill_edges(const int* __restrict__ src, const int* __restrict__ dst,
                           const float* __restrict__ dinv, int* __restrict__ cursor,
                           int* __restrict__ srcs, float* __restrict__ nrm, int E) {
    int e = blockIdx.x * 256 + threadIdx.x;
    if (e >= E) return;
    int s = src[e], d = dst[e];
    int pos = atomAddI(&cursor[d], 1);
    srcs[pos] = s;
    nrm[pos] = dinv[s] * dinv[d];
}

// ---------------- GEMM: Y[N,128] = (relu?)X[N,128] @ W[128,128] ----------------
__global__ __launch_bounds__(256) void gemm128(const float* __restrict__ X,
                                               const float* __restrict__ W,
                                               float* __restrict__ Y,
                                               int N, int relu_in) {
    __shared__ float Wl[128 * 128];
    __shared__ float Xl[32 * 128];
    const int tid = threadIdx.x;

    {
        const float4* W4 = (const float4*)W;
        float4* Wl4 = (float4*)Wl;
#pragma unroll
        for (int i = 0; i < 16; i++) Wl4[tid + i * 256] = W4[tid + i * 256];
    }
    const int row0 = blockIdx.x * 32;
    {
        const float4* X4 = (const float4*)X;
        float4* Xl4 = (float4*)Xl;
#pragma unroll
        for (int i = 0; i < 4; i++) {
            int idx = tid + i * 256;          // 0..1023
            int r = idx >> 5;
            float4 v;
            if (row0 + r < N) v = X4[(size_t)(row0 + r) * 32 + (idx & 31)];
            else v = make_float4(0.f, 0.f, 0.f, 0.f);
            if (relu_in) {
                v.x = fmaxf(v.x, 0.f); v.y = fmaxf(v.y, 0.f);
                v.z = fmaxf(v.z, 0.f); v.w = fmaxf(v.w, 0.f);
            }
            Xl4[idx] = v;
        }
    }
    __syncthreads();

    const int cg = tid & 31;   // col group (4 cols)
    const int rg = tid >> 5;   // row group (4 rows)
    float acc[4][4] = {};
    const float4* Wl4 = (const float4*)Wl;
#pragma unroll 4
    for (int k = 0; k < 128; k++) {
        float4 w = Wl4[k * 32 + cg];
        float x0 = Xl[(rg * 4 + 0) * 128 + k];
        float x1 = Xl[(rg * 4 + 1) * 128 + k];
        float x2 = Xl[(rg * 4 + 2) * 128 + k];
        float x3 = Xl[(rg * 4 + 3) * 128 + k];
        acc[0][0] += x0 * w.x; acc[0][1] += x0 * w.y; acc[0][2] += x0 * w.z; acc[0][3] += x0 * w.w;
        acc[1][0] += x1 * w.x; acc[1][1] += x1 * w.y; acc[1][2] += x1 * w.z; acc[1][3] += x1 * w.w;
        acc[2][0] += x2 * w.x; acc[2][1] += x2 * w.y; acc[2][2] += x2 * w.z; acc[2][3] += x2 * w.w;
        acc[3][0] += x3 * w.x; acc[3][1] += x3 * w.y; acc[3][2] += x3 * w.z; acc[3][3] += x3 * w.w;
    }
#pragma unroll
    for (int i = 0; i < 4; i++) {
        int r = row0 + rg * 4 + i;
        if (r < N)
            ((float4*)Y)[(size_t)r * 32 + cg] =
                make_float4(acc[i][0], acc[i][1], acc[i][2], acc[i][3]);
    }
}

// ---------------- CSR aggregate: B[i] = A[i]*dinv[i]^2 + b + sum_j A[srcs[j]]*nrm[j] ----------------
// 256 threads = 4 nodes x 64 lanes; 2 floats per lane.
__global__ __launch_bounds__(256) void aggregate(const float* __restrict__ A,
                                                 const float* __restrict__ dinv,
                                                 const int* __restrict__ off,
                                                 const int* __restrict__ srcs,
                                                 const float* __restrict__ nrm,
                                                 const float* __restrict__ bias,
                                                 float* __restrict__ B, int N) {
    int node = blockIdx.x * 4 + (threadIdx.x >> 6);
    if (node >= N) return;
    int lane = threadIdx.x & 63;
    float di = dinv[node];
    float2 a = ((const float2*)(A + (size_t)node * DHID))[lane];
    float2 bb = ((const float2*)bias)[lane];
    float accx = a.x * di * di + bb.x;
    float accy = a.y * di * di + bb.y;
    int j = off[node], jend = off[node + 1];
    // unroll by 2 for a little more MLP
    for (; j + 1 < jend; j += 2) {
        int s0 = srcs[j],     s1 = srcs[j + 1];
        float w0 = nrm[j],    w1 = nrm[j + 1];
        float2 v0 = ((const float2*)(A + (size_t)s0 * DHID))[lane];
        float2 v1 = ((const float2*)(A + (size_t)s1 * DHID))[lane];
        accx += v0.x * w0 + v1.x * w1;
        accy += v0.y * w0 + v1.y * w1;
    }
    if (j < jend) {
        int s = srcs[j];
        float w = nrm[j];
        float2 v = ((const float2*)(A + (size_t)s * DHID))[lane];
        accx += v.x * w;
        accy += v.y * w;
    }
    ((float2*)(B + (size_t)node * DHID))[lane] = make_float2(accx, accy);
}

// ---------------- fused pool + GRU + relu + layernorm + linear ----------------
__global__ __launch_bounds__(128) void pool_gru_head(const float* __restrict__ B,
                                                     const int* __restrict__ batch,
                                                     const float* __restrict__ W_ih,
                                                     const float* __restrict__ b_ih,
                                                     const float* __restrict__ b_hh,
                                                     const float* __restrict__ W_lin,
                                                     const float* __restrict__ b_lin,
                                                     float* __restrict__ out,
                                                     int N, int G) {
    __shared__ float Wl[128 * 129];
    __shared__ float gl[128];
    __shared__ float red[2];
    __shared__ int se[2];
    const int t = threadIdx.x;
    const int g = blockIdx.x;

    if (t < 2) {
        int target = g + t, lo = 0, hi = N;
        while (lo < hi) {
            int mid = (lo + hi) >> 1;
            if (batch[mid] < target) lo = mid + 1; else hi = mid;
        }
        se[t] = lo;
    }
    __syncthreads();
    const int s = se[0], e = se[1];

    float sum = 0.f;
    for (int r = s; r < e; r++) sum += B[(size_t)r * DHID + t];
    float gv = sum / fmaxf((float)(e - s), 1.0f);
    gl[t] = gv;

    float dot[3];
#pragma unroll
    for (int ch = 0; ch < 3; ch++) {
        __syncthreads();
        const float* Wc = W_ih + ch * 128 * 128;
        for (int i = t; i < 128 * 128; i += 128)
            Wl[(i >> 7) * 129 + (i & 127)] = Wc[i];
        __syncthreads();
        float acc = 0.f;
        const float* wr = &Wl[t * 129];
#pragma unroll 4
        for (int k = 0; k < 128; k++) acc += gl[k] * wr[k];
        dot[ch] = acc;
    }

    float rg = 1.f / (1.f + expf(-(dot[0] + b_ih[t] + b_hh[t])));
    float zg = 1.f / (1.f + expf(-(dot[1] + b_ih[128 + t] + b_hh[128 + t])));
    float ng = tanhf(dot[2] + b_ih[256 + t] + rg * b_hh[256 + t]);
    float y = fmaxf((1.f - zg) * ng, 0.f);   // h0 = 0, then relu

    auto blockSum = [&](float v) -> float {
#pragma unroll
        for (int o = 1; o < 64; o <<= 1) v += __shfl_xor(v, o);
        __syncthreads();
        if ((t & 63) == 0) red[t >> 6] = v;
        __syncthreads();
        return red[0] + red[1];
    };

    float mu = blockSum(y) * (1.f / 128.f);
    float dy = y - mu;
    float var = blockSum(dy * dy) * (1.f / 128.f);
    float yn = dy * rsqrtf(var + 1e-5f);
    float tot = blockSum(yn * W_lin[t]);
    if (t == 0) out[g] = tot + b_lin[0];
}

extern "C" void kernel_launch(void* const* d_in, const int* in_sizes, int n_in,
                              void* d_out, int out_size, void* d_ws, size_t ws_size,
                              hipStream_t stream) {
    const float* x     = (const float*)d_in[0];
    const int*   ei    = (const int*)d_in[1];
    const int*   batch = (const int*)d_in[2];
    const float* W1    = (const float*)d_in[3];
    const float* b1    = (const float*)d_in[4];
    const float* W2    = (const float*)d_in[5];
    const float* b2    = (const float*)d_in[6];
    const float* W_ih  = (const float*)d_in[7];
    // d_in[8] = W_hh: unused (h0 == 0)
    const float* b_ih  = (const float*)d_in[9];
    const float* b_hh  = (const float*)d_in[10];
    const float* W_lin = (const float*)d_in[11];
    const float* b_lin = (const float*)d_in[12];
    float* out = (float*)d_out;

    const int N = in_sizes[0] / DHID;
    const int E = in_sizes[1] / 2;
    const int G = out_size;
    const int* src = ei;
    const int* dst = ei + E;

    auto align256 = [](size_t v) { return (v + 255) & ~(size_t)255; };

    char* p = (char*)d_ws;
    size_t used = 0;
    auto carve = [&](size_t bytes) -> char* {
        char* q = p + used;
        used += align256(bytes);
        return q;
    };

    int*   cnt    = (int*)carve((size_t)N * 4);
    int*   off    = (int*)carve(((size_t)N + 1) * 4);
    int*   cursor = (int*)carve((size_t)N * 4);
    int*   bsum   = (int*)carve(4096 * 4);
    float* dinv   = (float*)carve((size_t)N * 4);
    int*   srcs   = (int*)carve((size_t)E * 4);
    float* nrm    = (float*)carve((size_t)E * 4);
    size_t mat_bytes = (size_t)N * DHID * sizeof(float);
    float* A = (float*)carve(mat_bytes);
    float* B;
    if (ws_size >= used + mat_bytes) {
        B = (float*)carve(mat_bytes);
    } else {
        // fall back to overwriting x (harness restores inputs before every launch;
        // x is fully consumed by the first GEMM before B is written)
        B = (float*)d_in[0];
    }

    dim3 blk(256);
    int nb_n  = (N + 255) / 256;
    int nb_e  = (E + 255) / 256;
    int nb_g  = (N + 31) / 32;
    int nb_ag = (N + 3) / 4;
    int n_scan_blocks = nb_n;

    // ---- CSR build (once; reused by both layers) ----
    zero_counts<<<nb_n, blk, 0, stream>>>(cnt, N);
    cnt_accum<<<nb_e, blk, 0, stream>>>(dst, cnt, E);
    dinv_from_cnt<<<nb_n, blk, 0, stream>>>(cnt, dinv, N);
    scan_block<<<n_scan_blocks, blk, 0, stream>>>(cnt, off, bsum, N);
    scan_bsums<<<1, dim3(512), 0, stream>>>(bsum, n_scan_blocks);
    add_offsets<<<nb_n, blk, 0, stream>>>(off, bsum, cursor, N, E);
    fill_edges<<<nb_e, blk, 0, stream>>>(src, dst, dinv, cursor, srcs, nrm, E);

    // ---- layer 1 ----
    gemm128<<<nb_g, blk, 0, stream>>>(x, W1, A, N, 0);
    aggregate<<<nb_ag, blk, 0, stream>>>(A, dinv, off, srcs, nrm, b1, B, N);

    // ---- layer 2 (relu fused into GEMM input read) ----
    gemm128<<<nb_g, blk, 0, stream>>>(B, W2, A, N, 1);
    aggregate<<<nb_ag, blk, 0, stream>>>(A, dinv, off, srcs, nrm, b2, B, N);

    // ---- pool + GRU + relu + layernorm + linear ----
    pool_gru_head<<<G, dim3(128), 0, stream>>>(B, batch, W_ih, b_ih, b_hh,
                                               W_lin, b_lin, out, N, G);
}

// Round 3
// 647.842 us; speedup vs baseline: 4.7724x; 1.2599x over previous
//
#include <hip/hip_runtime.h>
#include <hip/hip_bf16.h>
#include <math.h>

#define DHID 128

__device__ __forceinline__ int atomAddI(int* p, int v) {
    return __hip_atomic_fetch_add(p, v, __ATOMIC_RELAXED, __HIP_MEMORY_SCOPE_AGENT);
}

// ---------------- CSR build ----------------
__global__ void zero_counts(int* cnt, int N) {
    int i = blockIdx.x * 256 + threadIdx.x;
    if (i < N) cnt[i] = 0;
}

__global__ void cnt_accum(const int* __restrict__ dst, int* __restrict__ cnt, int E) {
    int e = blockIdx.x * 256 + threadIdx.x;
    if (e < E) atomAddI(&cnt[dst[e]], 1);
}

__global__ void dinv_from_cnt(const int* __restrict__ cnt, float* __restrict__ dinv, int N) {
    int i = blockIdx.x * 256 + threadIdx.x;
    if (i < N) dinv[i] = rsqrtf((float)cnt[i] + 1.0f);
}

__global__ __launch_bounds__(256) void scan_block(const int* __restrict__ cnt,
                                                  int* __restrict__ off,
                                                  int* __restrict__ bsum, int N) {
    __shared__ int sh[256];
    int t = threadIdx.x;
    int i = blockIdx.x * 256 + t;
    int v = (i < N) ? cnt[i] : 0;
    sh[t] = v;
    __syncthreads();
#pragma unroll
    for (int o = 1; o < 256; o <<= 1) {
        int x = (t >= o) ? sh[t - o] : 0;
        __syncthreads();
        sh[t] += x;
        __syncthreads();
    }
    if (i < N) off[i] = sh[t] - v;
    if (t == 255) bsum[blockIdx.x] = sh[255];
}

__global__ __launch_bounds__(512) void scan_bsums(int* bsum, int nb) {
    __shared__ int sh[512];
    int t = threadIdx.x;
    int carry = 0;
    for (int base = 0; base < nb; base += 512) {
        int idx = base + t;
        int v = (idx < nb) ? bsum[idx] : 0;
        sh[t] = v;
        __syncthreads();
#pragma unroll
        for (int o = 1; o < 512; o <<= 1) {
            int x = (t >= o) ? sh[t - o] : 0;
            __syncthreads();
            sh[t] += x;
            __syncthreads();
        }
        if (idx < nb) bsum[idx] = sh[t] - v + carry;
        carry += sh[511];
        __syncthreads();
    }
}

__global__ void add_offsets(int* __restrict__ off, const int* __restrict__ bsum,
                            int* __restrict__ cursor, int N, int E) {
    int i = blockIdx.x * 256 + threadIdx.x;
    if (i < N) {
        int o = off[i] + bsum[i >> 8];
        off[i] = o;
        cursor[i] = o;
    }
    if (i == 0) off[N] = E;
}

__global__ void fill_edges(const int* __restrict__ src, const int* __restrict__ dst,
                           const float* __restrict__ dinv, int* __restrict__ cursor,
                           int* __restrict__ srcs, float* __restrict__ nrm, int E) {
    int e = blockIdx.x * 256 + threadIdx.x;
    if (e >= E) return;
    int s = src[e], d = dst[e];
    int pos = atomAddI(&cursor[d], 1);
    srcs[pos] = s;
    nrm[pos] = dinv[s] * dinv[d];
}

// ---------------- GEMM: Y[N,128] = (relu?)X[N,128] @ W[128,128] ----------------
__global__ __launch_bounds__(256) void gemm128(const float* __restrict__ X,
                                               const float* __restrict__ W,
                                               float* __restrict__ Y,
                                               int N, int relu_in) {
    __shared__ float Wl[128 * 128];
    __shared__ float Xl[32 * 128];
    const int tid = threadIdx.x;

    {
        const float4* W4 = (const float4*)W;
        float4* Wl4 = (float4*)Wl;
#pragma unroll
        for (int i = 0; i < 16; i++) Wl4[tid + i * 256] = W4[tid + i * 256];
    }
    const int row0 = blockIdx.x * 32;
    {
        const float4* X4 = (const float4*)X;
        float4* Xl4 = (float4*)Xl;
#pragma unroll
        for (int i = 0; i < 4; i++) {
            int idx = tid + i * 256;
            int r = idx >> 5;
            float4 v;
            if (row0 + r < N) v = X4[(size_t)(row0 + r) * 32 + (idx & 31)];
            else v = make_float4(0.f, 0.f, 0.f, 0.f);
            if (relu_in) {
                v.x = fmaxf(v.x, 0.f); v.y = fmaxf(v.y, 0.f);
                v.z = fmaxf(v.z, 0.f); v.w = fmaxf(v.w, 0.f);
            }
            Xl4[idx] = v;
        }
    }
    __syncthreads();

    const int cg = tid & 31;
    const int rg = tid >> 5;
    float acc[4][4] = {};
    const float4* Wl4 = (const float4*)Wl;
#pragma unroll 4
    for (int k = 0; k < 128; k++) {
        float4 w = Wl4[k * 32 + cg];
        float x0 = Xl[(rg * 4 + 0) * 128 + k];
        float x1 = Xl[(rg * 4 + 1) * 128 + k];
        float x2 = Xl[(rg * 4 + 2) * 128 + k];
        float x3 = Xl[(rg * 4 + 3) * 128 + k];
        acc[0][0] += x0 * w.x; acc[0][1] += x0 * w.y; acc[0][2] += x0 * w.z; acc[0][3] += x0 * w.w;
        acc[1][0] += x1 * w.x; acc[1][1] += x1 * w.y; acc[1][2] += x1 * w.z; acc[1][3] += x1 * w.w;
        acc[2][0] += x2 * w.x; acc[2][1] += x2 * w.y; acc[2][2] += x2 * w.z; acc[2][3] += x2 * w.w;
        acc[3][0] += x3 * w.x; acc[3][1] += x3 * w.y; acc[3][2] += x3 * w.z; acc[3][3] += x3 * w.w;
    }
#pragma unroll
    for (int i = 0; i < 4; i++) {
        int r = row0 + rg * 4 + i;
        if (r < N)
            ((float4*)Y)[(size_t)r * 32 + cg] =
                make_float4(acc[i][0], acc[i][1], acc[i][2], acc[i][3]);
    }
}

// ---------------- CSR aggregate v2: float4 gathers, 2 edges in flight ----------------
// 256 threads = 4 nodes x 64 lanes. Lanes 0-31 process even-position edges,
// lanes 32-63 odd-position; each lane holds float4 (16B) of the 512B row.
__global__ __launch_bounds__(256) void aggregate(const float* __restrict__ A,
                                                 const float* __restrict__ dinv,
                                                 const int* __restrict__ off,
                                                 const int* __restrict__ srcs,
                                                 const float* __restrict__ nrm,
                                                 const float* __restrict__ bias,
                                                 float* __restrict__ B, int N) {
    int node = blockIdx.x * 4 + (threadIdx.x >> 6);
    if (node >= N) return;
    int lane = threadIdx.x & 63;
    int half = lane >> 5;
    int l32  = lane & 31;
    float di = dinv[node];
    float4 acc;
    if (half == 0) {
        float4 a = ((const float4*)(A + (size_t)node * DHID))[l32];
        float4 bb = ((const float4*)bias)[l32];
        float s = di * di;
        acc = make_float4(a.x * s + bb.x, a.y * s + bb.y, a.z * s + bb.z, a.w * s + bb.w);
    } else {
        acc = make_float4(0.f, 0.f, 0.f, 0.f);
    }
    int j = off[node] + half;
    int jend = off[node + 1];
    // unrolled: 4 gathers in flight per wave iteration
    for (; j + 2 < jend; j += 4) {
        int s0 = srcs[j];     float w0 = nrm[j];
        int s1 = srcs[j + 2]; float w1 = nrm[j + 2];
        float4 v0 = ((const float4*)(A + (size_t)s0 * DHID))[l32];
        float4 v1 = ((const float4*)(A + (size_t)s1 * DHID))[l32];
        acc.x += v0.x * w0 + v1.x * w1;
        acc.y += v0.y * w0 + v1.y * w1;
        acc.z += v0.z * w0 + v1.z * w1;
        acc.w += v0.w * w0 + v1.w * w1;
    }
    if (j < jend) {
        int s = srcs[j];
        float w = nrm[j];
        float4 v = ((const float4*)(A + (size_t)s * DHID))[l32];
        acc.x += v.x * w; acc.y += v.y * w; acc.z += v.z * w; acc.w += v.w * w;
    }
    acc.x += __shfl_xor(acc.x, 32);
    acc.y += __shfl_xor(acc.y, 32);
    acc.z += __shfl_xor(acc.z, 32);
    acc.w += __shfl_xor(acc.w, 32);
    if (half == 0)
        ((float4*)(B + (size_t)node * DHID))[l32] = acc;
}

// ---------------- pool: per-graph mean ----------------
__global__ __launch_bounds__(256) void pool_mean(const float* __restrict__ B,
                                                 const int* __restrict__ batch,
                                                 float* __restrict__ g, int N, int G) {
    __shared__ int se[2];
    __shared__ float red[128];
    const int t = threadIdx.x;
    const int gr = blockIdx.x;
    if (t < 2) {
        int target = gr + t, lo = 0, hi = N;
        while (lo < hi) {
            int mid = (lo + hi) >> 1;
            if (batch[mid] < target) lo = mid + 1; else hi = mid;
        }
        se[t] = lo;
    }
    __syncthreads();
    const int s = se[0], e = se[1];
    const int col = t & 127, rh = t >> 7;
    float sum = 0.f;
    for (int r = s + rh; r < e; r += 2) sum += B[(size_t)r * DHID + col];
    if (rh == 1) red[col] = sum;
    __syncthreads();
    if (rh == 0) {
        float tot = sum + red[col];
        g[(size_t)gr * DHID + col] = tot / fmaxf((float)(e - s), 1.0f);
    }
}

// ---------------- transpose W_ih into 3 chunks of [k=128][j=128] ----------------
__global__ void transpose_wih(const float* __restrict__ W_ih, float* __restrict__ Wt) {
    int idx = blockIdx.x * 256 + threadIdx.x;   // 3*128*128 elements
    if (idx >= 3 * 128 * 128) return;
    int ch = idx >> 14;
    int k = (idx >> 7) & 127;
    int jj = idx & 127;
    Wt[idx] = W_ih[((size_t)ch * 128 + jj) * 128 + k];
}

// ---------------- head GEMM: gi[ch][G,128] = g[G,128] @ Wt[ch] ----------------
__global__ __launch_bounds__(256) void head_gemm(const float* __restrict__ X,
                                                 const float* __restrict__ Wt,
                                                 float* __restrict__ gi, int G) {
    __shared__ float Wl[128 * 128];
    __shared__ float Xl[32 * 128];
    const int tid = threadIdx.x;
    const int ch = blockIdx.y;
    const float* W = Wt + (size_t)ch * 16384;
    float* Y = gi + (size_t)ch * G * DHID;

    {
        const float4* W4 = (const float4*)W;
        float4* Wl4 = (float4*)Wl;
#pragma unroll
        for (int i = 0; i < 16; i++) Wl4[tid + i * 256] = W4[tid + i * 256];
    }
    const int row0 = blockIdx.x * 32;
    {
        const float4* X4 = (const float4*)X;
        float4* Xl4 = (float4*)Xl;
#pragma unroll
        for (int i = 0; i < 4; i++) {
            int idx = tid + i * 256;
            int r = idx >> 5;
            float4 v;
            if (row0 + r < G) v = X4[(size_t)(row0 + r) * 32 + (idx & 31)];
            else v = make_float4(0.f, 0.f, 0.f, 0.f);
            Xl4[idx] = v;
        }
    }
    __syncthreads();

    const int cg = tid & 31;
    const int rg = tid >> 5;
    float acc[4][4] = {};
    const float4* Wl4 = (const float4*)Wl;
#pragma unroll 4
    for (int k = 0; k < 128; k++) {
        float4 w = Wl4[k * 32 + cg];
        float x0 = Xl[(rg * 4 + 0) * 128 + k];
        float x1 = Xl[(rg * 4 + 1) * 128 + k];
        float x2 = Xl[(rg * 4 + 2) * 128 + k];
        float x3 = Xl[(rg * 4 + 3) * 128 + k];
        acc[0][0] += x0 * w.x; acc[0][1] += x0 * w.y; acc[0][2] += x0 * w.z; acc[0][3] += x0 * w.w;
        acc[1][0] += x1 * w.x; acc[1][1] += x1 * w.y; acc[1][2] += x1 * w.z; acc[1][3] += x1 * w.w;
        acc[2][0] += x2 * w.x; acc[2][1] += x2 * w.y; acc[2][2] += x2 * w.z; acc[2][3] += x2 * w.w;
        acc[3][0] += x3 * w.x; acc[3][1] += x3 * w.y; acc[3][2] += x3 * w.z; acc[3][3] += x3 * w.w;
    }
#pragma unroll
    for (int i = 0; i < 4; i++) {
        int r = row0 + rg * 4 + i;
        if (r < G)
            ((float4*)Y)[(size_t)r * 32 + cg] =
                make_float4(acc[i][0], acc[i][1], acc[i][2], acc[i][3]);
    }
}

// ---------------- gates + relu + layernorm + linear ----------------
__global__ __launch_bounds__(128) void gate_ln_head(const float* __restrict__ gi,
                                                    const float* __restrict__ b_ih,
                                                    const float* __restrict__ b_hh,
                                                    const float* __restrict__ W_lin,
                                                    const float* __restrict__ b_lin,
                                                    float* __restrict__ out, int G) {
    __shared__ float red[2];
    const int t = threadIdx.x;
    const int g = blockIdx.x;

    float d0 = gi[(size_t)g * DHID + t];
    float d1 = gi[(size_t)(G + g) * DHID + t];
    float d2 = gi[(size_t)(2 * G + g) * DHID + t];

    float rg = 1.f / (1.f + expf(-(d0 + b_ih[t] + b_hh[t])));
    float zg = 1.f / (1.f + expf(-(d1 + b_ih[128 + t] + b_hh[128 + t])));
    float ng = tanhf(d2 + b_ih[256 + t] + rg * b_hh[256 + t]);
    float y = fmaxf((1.f - zg) * ng, 0.f);

    auto blockSum = [&](float v) -> float {
#pragma unroll
        for (int o = 1; o < 64; o <<= 1) v += __shfl_xor(v, o);
        __syncthreads();
        if ((t & 63) == 0) red[t >> 6] = v;
        __syncthreads();
        return red[0] + red[1];
    };

    float mu = blockSum(y) * (1.f / 128.f);
    float dy = y - mu;
    float var = blockSum(dy * dy) * (1.f / 128.f);
    float yn = dy * rsqrtf(var + 1e-5f);
    float tot = blockSum(yn * W_lin[t]);
    if (t == 0) out[g] = tot + b_lin[0];
}

extern "C" void kernel_launch(void* const* d_in, const int* in_sizes, int n_in,
                              void* d_out, int out_size, void* d_ws, size_t ws_size,
                              hipStream_t stream) {
    const float* x     = (const float*)d_in[0];
    const int*   ei    = (const int*)d_in[1];
    const int*   batch = (const int*)d_in[2];
    const float* W1    = (const float*)d_in[3];
    const float* b1    = (const float*)d_in[4];
    const float* W2    = (const float*)d_in[5];
    const float* b2    = (const float*)d_in[6];
    const float* W_ih  = (const float*)d_in[7];
    // d_in[8] = W_hh unused (h0 == 0)
    const float* b_ih  = (const float*)d_in[9];
    const float* b_hh  = (const float*)d_in[10];
    const float* W_lin = (const float*)d_in[11];
    const float* b_lin = (const float*)d_in[12];
    float* out = (float*)d_out;

    const int N = in_sizes[0] / DHID;
    const int E = in_sizes[1] / 2;
    const int G = out_size;
    const int* src = ei;
    const int* dst = ei + E;

    auto align256 = [](size_t v) { return (v + 255) & ~(size_t)255; };
    char* p = (char*)d_ws;
    size_t used = 0;
    auto carve = [&](size_t bytes) -> char* {
        char* q = p + used;
        used += align256(bytes);
        return q;
    };

    int*   cnt    = (int*)carve((size_t)N * 4);
    int*   off    = (int*)carve(((size_t)N + 1) * 4);
    int*   cursor = (int*)carve((size_t)N * 4);
    int*   bsum   = (int*)carve(4096 * 4);
    float* dinv   = (float*)carve((size_t)N * 4);
    int*   srcs   = (int*)carve((size_t)E * 4);
    float* nrm    = (float*)carve((size_t)E * 4);
    float* gbuf   = (float*)carve((size_t)G * DHID * 4);
    float* Wt     = (float*)carve((size_t)3 * 128 * 128 * 4);
    float* gi     = (float*)carve((size_t)3 * G * DHID * 4);
    size_t mat_bytes = (size_t)N * DHID * sizeof(float);
    float* A = (float*)carve(mat_bytes);
    float* B;
    if (ws_size >= used + mat_bytes) {
        B = (float*)carve(mat_bytes);
    } else {
        B = (float*)d_in[0];   // harness restores inputs before every launch
    }

    dim3 blk(256);
    int nb_n  = (N + 255) / 256;
    int nb_e  = (E + 255) / 256;
    int nb_g  = (N + 31) / 32;
    int nb_ag = (N + 3) / 4;

    // ---- CSR build ----
    zero_counts<<<nb_n, blk, 0, stream>>>(cnt, N);
    cnt_accum<<<nb_e, blk, 0, stream>>>(dst, cnt, E);
    dinv_from_cnt<<<nb_n, blk, 0, stream>>>(cnt, dinv, N);
    scan_block<<<nb_n, blk, 0, stream>>>(cnt, off, bsum, N);
    scan_bsums<<<1, dim3(512), 0, stream>>>(bsum, nb_n);
    add_offsets<<<nb_n, blk, 0, stream>>>(off, bsum, cursor, N, E);
    fill_edges<<<nb_e, blk, 0, stream>>>(src, dst, dinv, cursor, srcs, nrm, E);

    // ---- layer 1 ----
    gemm128<<<nb_g, blk, 0, stream>>>(x, W1, A, N, 0);
    aggregate<<<nb_ag, blk, 0, stream>>>(A, dinv, off, srcs, nrm, b1, B, N);

    // ---- layer 2 ----
    gemm128<<<nb_g, blk, 0, stream>>>(B, W2, A, N, 1);
    aggregate<<<nb_ag, blk, 0, stream>>>(A, dinv, off, srcs, nrm, b2, B, N);

    // ---- head ----
    pool_mean<<<G, blk, 0, stream>>>(B, batch, gbuf, N, G);
    transpose_wih<<<(3 * 128 * 128 + 255) / 256, blk, 0, stream>>>(W_ih, Wt);
    head_gemm<<<dim3((G + 31) / 32, 3), blk, 0, stream>>>(gbuf, Wt, gi, G);
    gate_ln_head<<<G, dim3(128), 0, stream>>>(gi, b_ih, b_hh, W_lin, b_lin, out, G);
}

// Round 4
// 561.946 us; speedup vs baseline: 5.5018x; 1.1529x over previous
//
#include <hip/hip_runtime.h>
#include <hip/hip_bf16.h>
#include <math.h>

#define DHID 128

__device__ __forceinline__ int atomAddI(int* p, int v) {
    return __hip_atomic_fetch_add(p, v, __ATOMIC_RELAXED, __HIP_MEMORY_SCOPE_AGENT);
}
__device__ __forceinline__ float bf_lo(unsigned u) { return __uint_as_float(u << 16); }
__device__ __forceinline__ float bf_hi(unsigned u) { return __uint_as_float(u & 0xffff0000u); }
__device__ __forceinline__ unsigned pack_bf16x2(float a, float b) {
    unsigned ua = __float_as_uint(a);
    unsigned ub = __float_as_uint(b);
    ua = (ua + 0x7fffu + ((ua >> 16) & 1u)) >> 16;   // RNE
    ub = (ub + 0x7fffu + ((ub >> 16) & 1u)) & 0xffff0000u;
    return ua | ub;
}

// ---------------- CSR build ----------------
__global__ void zero_counts(int* cnt, int N) {
    int i = blockIdx.x * 256 + threadIdx.x;
    if (i < N) cnt[i] = 0;
}

__global__ void cnt_accum(const int* __restrict__ dst, int* __restrict__ cnt, int E) {
    int e = blockIdx.x * 256 + threadIdx.x;
    if (e < E) atomAddI(&cnt[dst[e]], 1);
}

__global__ void dinv_from_cnt(const int* __restrict__ cnt, float* __restrict__ dinv, int N) {
    int i = blockIdx.x * 256 + threadIdx.x;
    if (i < N) dinv[i] = rsqrtf((float)cnt[i] + 1.0f);
}

__global__ __launch_bounds__(256) void scan_block(const int* __restrict__ cnt,
                                                  int* __restrict__ off,
                                                  int* __restrict__ bsum, int N) {
    __shared__ int sh[256];
    int t = threadIdx.x;
    int i = blockIdx.x * 256 + t;
    int v = (i < N) ? cnt[i] : 0;
    sh[t] = v;
    __syncthreads();
#pragma unroll
    for (int o = 1; o < 256; o <<= 1) {
        int x = (t >= o) ? sh[t - o] : 0;
        __syncthreads();
        sh[t] += x;
        __syncthreads();
    }
    if (i < N) off[i] = sh[t] - v;
    if (t == 255) bsum[blockIdx.x] = sh[255];
}

__global__ __launch_bounds__(512) void scan_bsums(int* bsum, int nb) {
    __shared__ int sh[512];
    int t = threadIdx.x;
    int carry = 0;
    for (int base = 0; base < nb; base += 512) {
        int idx = base + t;
        int v = (idx < nb) ? bsum[idx] : 0;
        sh[t] = v;
        __syncthreads();
#pragma unroll
        for (int o = 1; o < 512; o <<= 1) {
            int x = (t >= o) ? sh[t - o] : 0;
            __syncthreads();
            sh[t] += x;
            __syncthreads();
        }
        if (idx < nb) bsum[idx] = sh[t] - v + carry;
        carry += sh[511];
        __syncthreads();
    }
}

__global__ void add_offsets(int* __restrict__ off, const int* __restrict__ bsum,
                            int* __restrict__ cursor, int N, int E) {
    int i = blockIdx.x * 256 + threadIdx.x;
    if (i < N) {
        int o = off[i] + bsum[i >> 8];
        off[i] = o;
        cursor[i] = o;
    }
    if (i == 0) off[N] = E;
}

// one fused 8B record per edge: {src, norm-bits}
__global__ void fill_edges(const int* __restrict__ src, const int* __restrict__ dst,
                           const float* __restrict__ dinv, int* __restrict__ cursor,
                           int2* __restrict__ rec, int E) {
    int e = blockIdx.x * 256 + threadIdx.x;
    if (e >= E) return;
    int s = src[e], d = dst[e];
    int pos = atomAddI(&cursor[d], 1);
    rec[pos] = make_int2(s, __float_as_int(dinv[s] * dinv[d]));
}

// ---------------- GEMM: Ybf16[N,128] = (relu?)X[N,128] @ W[128,128] ----------------
__global__ __launch_bounds__(256) void gemm128(const float* __restrict__ X,
                                               const float* __restrict__ W,
                                               unsigned short* __restrict__ Y,
                                               int N, int relu_in) {
    __shared__ float Wl[128 * 128];
    __shared__ float Xl[32 * 128];
    const int tid = threadIdx.x;

    {
        const float4* W4 = (const float4*)W;
        float4* Wl4 = (float4*)Wl;
#pragma unroll
        for (int i = 0; i < 16; i++) Wl4[tid + i * 256] = W4[tid + i * 256];
    }
    const int row0 = blockIdx.x * 32;
    {
        const float4* X4 = (const float4*)X;
        float4* Xl4 = (float4*)Xl;
#pragma unroll
        for (int i = 0; i < 4; i++) {
            int idx = tid + i * 256;
            int r = idx >> 5;
            float4 v;
            if (row0 + r < N) v = X4[(size_t)(row0 + r) * 32 + (idx & 31)];
            else v = make_float4(0.f, 0.f, 0.f, 0.f);
            if (relu_in) {
                v.x = fmaxf(v.x, 0.f); v.y = fmaxf(v.y, 0.f);
                v.z = fmaxf(v.z, 0.f); v.w = fmaxf(v.w, 0.f);
            }
            Xl4[idx] = v;
        }
    }
    __syncthreads();

    const int cg = tid & 31;
    const int rg = tid >> 5;
    float acc[4][4] = {};
    const float4* Wl4 = (const float4*)Wl;
    for (int k0 = 0; k0 < 128; k0 += 4) {
        float4 xr[4];
#pragma unroll
        for (int i = 0; i < 4; i++)
            xr[i] = *(const float4*)&Xl[(rg * 4 + i) * 128 + k0];  // broadcast across lanes
        float4 w0 = Wl4[(k0 + 0) * 32 + cg];
        float4 w1 = Wl4[(k0 + 1) * 32 + cg];
        float4 w2 = Wl4[(k0 + 2) * 32 + cg];
        float4 w3 = Wl4[(k0 + 3) * 32 + cg];
#pragma unroll
        for (int i = 0; i < 4; i++) {
            acc[i][0] += xr[i].x * w0.x + xr[i].y * w1.x + xr[i].z * w2.x + xr[i].w * w3.x;
            acc[i][1] += xr[i].x * w0.y + xr[i].y * w1.y + xr[i].z * w2.y + xr[i].w * w3.y;
            acc[i][2] += xr[i].x * w0.z + xr[i].y * w1.z + xr[i].z * w2.z + xr[i].w * w3.z;
            acc[i][3] += xr[i].x * w0.w + xr[i].y * w1.w + xr[i].z * w2.w + xr[i].w * w3.w;
        }
    }
#pragma unroll
    for (int i = 0; i < 4; i++) {
        int r = row0 + rg * 4 + i;
        if (r < N) {
            uint2 pk = make_uint2(pack_bf16x2(acc[i][0], acc[i][1]),
                                  pack_bf16x2(acc[i][2], acc[i][3]));
            *(uint2*)(Y + (size_t)r * DHID + cg * 4) = pk;
        }
    }
}

// ---------------- CSR aggregate: bf16 gathers, fp32 accumulate/output ----------------
// 256 threads = 4 nodes x 64 lanes; half-waves take even/odd edge positions;
// each lane holds 4 bf16 (8B) of the 256B row.
__global__ __launch_bounds__(256) void aggregate(const unsigned short* __restrict__ A,
                                                 const float* __restrict__ dinv,
                                                 const int* __restrict__ off,
                                                 const int2* __restrict__ rec,
                                                 const float* __restrict__ bias,
                                                 float* __restrict__ B, int N) {
    int node = blockIdx.x * 4 + (threadIdx.x >> 6);
    if (node >= N) return;
    int lane = threadIdx.x & 63;
    int half = lane >> 5;
    int l32  = lane & 31;
    float4 acc = make_float4(0.f, 0.f, 0.f, 0.f);
    if (half == 0) {
        float di = dinv[node];
        float s = di * di;
        uint2 v = ((const uint2*)(A + (size_t)node * DHID))[l32];
        float4 bb = ((const float4*)bias)[l32];
        acc.x = bf_lo(v.x) * s + bb.x;
        acc.y = bf_hi(v.x) * s + bb.y;
        acc.z = bf_lo(v.y) * s + bb.z;
        acc.w = bf_hi(v.y) * s + bb.w;
    }
    int j = off[node] + half;
    int jend = off[node + 1];
    for (; j + 2 < jend; j += 4) {
        int2 r0 = rec[j];
        int2 r1 = rec[j + 2];
        uint2 v0 = ((const uint2*)(A + (size_t)r0.x * DHID))[l32];
        uint2 v1 = ((const uint2*)(A + (size_t)r1.x * DHID))[l32];
        float w0 = __int_as_float(r0.y);
        float w1 = __int_as_float(r1.y);
        acc.x += bf_lo(v0.x) * w0 + bf_lo(v1.x) * w1;
        acc.y += bf_hi(v0.x) * w0 + bf_hi(v1.x) * w1;
        acc.z += bf_lo(v0.y) * w0 + bf_lo(v1.y) * w1;
        acc.w += bf_hi(v0.y) * w0 + bf_hi(v1.y) * w1;
    }
    if (j < jend) {
        int2 r = rec[j];
        uint2 v = ((const uint2*)(A + (size_t)r.x * DHID))[l32];
        float w = __int_as_float(r.y);
        acc.x += bf_lo(v.x) * w;
        acc.y += bf_hi(v.x) * w;
        acc.z += bf_lo(v.y) * w;
        acc.w += bf_hi(v.y) * w;
    }
    acc.x += __shfl_xor(acc.x, 32);
    acc.y += __shfl_xor(acc.y, 32);
    acc.z += __shfl_xor(acc.z, 32);
    acc.w += __shfl_xor(acc.w, 32);
    if (half == 0)
        ((float4*)(B + (size_t)node * DHID))[l32] = acc;
}

// ---------------- pool: per-graph mean ----------------
__global__ __launch_bounds__(256) void pool_mean(const float* __restrict__ B,
                                                 const int* __restrict__ batch,
                                                 float* __restrict__ g, int N, int G) {
    __shared__ int se[2];
    __shared__ float red[128];
    const int t = threadIdx.x;
    const int gr = blockIdx.x;
    if (t < 2) {
        int target = gr + t, lo = 0, hi = N;
        while (lo < hi) {
            int mid = (lo + hi) >> 1;
            if (batch[mid] < target) lo = mid + 1; else hi = mid;
        }
        se[t] = lo;
    }
    __syncthreads();
    const int s = se[0], e = se[1];
    const int col = t & 127, rh = t >> 7;
    float sum = 0.f;
    for (int r = s + rh; r < e; r += 2) sum += B[(size_t)r * DHID + col];
    if (rh == 1) red[col] = sum;
    __syncthreads();
    if (rh == 0) {
        float tot = sum + red[col];
        g[(size_t)gr * DHID + col] = tot / fmaxf((float)(e - s), 1.0f);
    }
}

// ---------------- transpose W_ih into 3 chunks of [k=128][j=128] ----------------
__global__ void transpose_wih(const float* __restrict__ W_ih, float* __restrict__ Wt) {
    int idx = blockIdx.x * 256 + threadIdx.x;
    if (idx >= 3 * 128 * 128) return;
    int ch = idx >> 14;
    int k = (idx >> 7) & 127;
    int jj = idx & 127;
    Wt[idx] = W_ih[((size_t)ch * 128 + jj) * 128 + k];
}

// ---------------- head GEMM: gi[ch][G,128] = g[G,128] @ Wt[ch] (fp32 out) ----------------
__global__ __launch_bounds__(256) void head_gemm(const float* __restrict__ X,
                                                 const float* __restrict__ Wt,
                                                 float* __restrict__ gi, int G) {
    __shared__ float Wl[128 * 128];
    __shared__ float Xl[32 * 128];
    const int tid = threadIdx.x;
    const int ch = blockIdx.y;
    const float* W = Wt + (size_t)ch * 16384;
    float* Y = gi + (size_t)ch * G * DHID;

    {
        const float4* W4 = (const float4*)W;
        float4* Wl4 = (float4*)Wl;
#pragma unroll
        for (int i = 0; i < 16; i++) Wl4[tid + i * 256] = W4[tid + i * 256];
    }
    const int row0 = blockIdx.x * 32;
    {
        const float4* X4 = (const float4*)X;
        float4* Xl4 = (float4*)Xl;
#pragma unroll
        for (int i = 0; i < 4; i++) {
            int idx = tid + i * 256;
            int r = idx >> 5;
            float4 v;
            if (row0 + r < G) v = X4[(size_t)(row0 + r) * 32 + (idx & 31)];
            else v = make_float4(0.f, 0.f, 0.f, 0.f);
            Xl4[idx] = v;
        }
    }
    __syncthreads();

    const int cg = tid & 31;
    const int rg = tid >> 5;
    float acc[4][4] = {};
    const float4* Wl4 = (const float4*)Wl;
    for (int k0 = 0; k0 < 128; k0 += 4) {
        float4 xr[4];
#pragma unroll
        for (int i = 0; i < 4; i++)
            xr[i] = *(const float4*)&Xl[(rg * 4 + i) * 128 + k0];
        float4 w0 = Wl4[(k0 + 0) * 32 + cg];
        float4 w1 = Wl4[(k0 + 1) * 32 + cg];
        float4 w2 = Wl4[(k0 + 2) * 32 + cg];
        float4 w3 = Wl4[(k0 + 3) * 32 + cg];
#pragma unroll
        for (int i = 0; i < 4; i++) {
            acc[i][0] += xr[i].x * w0.x + xr[i].y * w1.x + xr[i].z * w2.x + xr[i].w * w3.x;
            acc[i][1] += xr[i].x * w0.y + xr[i].y * w1.y + xr[i].z * w2.y + xr[i].w * w3.y;
            acc[i][2] += xr[i].x * w0.z + xr[i].y * w1.z + xr[i].z * w2.z + xr[i].w * w3.z;
            acc[i][3] += xr[i].x * w0.w + xr[i].y * w1.w + xr[i].z * w2.w + xr[i].w * w3.w;
        }
    }
#pragma unroll
    for (int i = 0; i < 4; i++) {
        int r = row0 + rg * 4 + i;
        if (r < G)
            ((float4*)Y)[(size_t)r * 32 + cg] =
                make_float4(acc[i][0], acc[i][1], acc[i][2], acc[i][3]);
    }
}

// ---------------- gates + relu + layernorm + linear ----------------
__global__ __launch_bounds__(128) void gate_ln_head(const float* __restrict__ gi,
                                                    const float* __restrict__ b_ih,
                                                    const float* __restrict__ b_hh,
                                                    const float* __restrict__ W_lin,
                                                    const float* __restrict__ b_lin,
                                                    float* __restrict__ out, int G) {
    __shared__ float red[2];
    const int t = threadIdx.x;
    const int g = blockIdx.x;

    float d0 = gi[(size_t)g * DHID + t];
    float d1 = gi[(size_t)(G + g) * DHID + t];
    float d2 = gi[(size_t)(2 * G + g) * DHID + t];

    float rg = 1.f / (1.f + expf(-(d0 + b_ih[t] + b_hh[t])));
    float zg = 1.f / (1.f + expf(-(d1 + b_ih[128 + t] + b_hh[128 + t])));
    float ng = tanhf(d2 + b_ih[256 + t] + rg * b_hh[256 + t]);
    float y = fmaxf((1.f - zg) * ng, 0.f);

    auto blockSum = [&](float v) -> float {
#pragma unroll
        for (int o = 1; o < 64; o <<= 1) v += __shfl_xor(v, o);
        __syncthreads();
        if ((t & 63) == 0) red[t >> 6] = v;
        __syncthreads();
        return red[0] + red[1];
    };

    float mu = blockSum(y) * (1.f / 128.f);
    float dy = y - mu;
    float var = blockSum(dy * dy) * (1.f / 128.f);
    float yn = dy * rsqrtf(var + 1e-5f);
    float tot = blockSum(yn * W_lin[t]);
    if (t == 0) out[g] = tot + b_lin[0];
}

extern "C" void kernel_launch(void* const* d_in, const int* in_sizes, int n_in,
                              void* d_out, int out_size, void* d_ws, size_t ws_size,
                              hipStream_t stream) {
    const float* x     = (const float*)d_in[0];
    const int*   ei    = (const int*)d_in[1];
    const int*   batch = (const int*)d_in[2];
    const float* W1    = (const float*)d_in[3];
    const float* b1    = (const float*)d_in[4];
    const float* W2    = (const float*)d_in[5];
    const float* b2    = (const float*)d_in[6];
    const float* W_ih  = (const float*)d_in[7];
    // d_in[8] = W_hh unused (h0 == 0)
    const float* b_ih  = (const float*)d_in[9];
    const float* b_hh  = (const float*)d_in[10];
    const float* W_lin = (const float*)d_in[11];
    const float* b_lin = (const float*)d_in[12];
    float* out = (float*)d_out;

    const int N = in_sizes[0] / DHID;
    const int E = in_sizes[1] / 2;
    const int G = out_size;
    const int* src = ei;
    const int* dst = ei + E;

    auto align256 = [](size_t v) { return (v + 255) & ~(size_t)255; };
    char* p = (char*)d_ws;
    size_t used = 0;
    auto carve = [&](size_t bytes) -> char* {
        char* q = p + used;
        used += align256(bytes);
        return q;
    };

    int*   cnt    = (int*)carve((size_t)N * 4);
    int*   off    = (int*)carve(((size_t)N + 1) * 4);
    int*   cursor = (int*)carve((size_t)N * 4);
    int*   bsum   = (int*)carve(4096 * 4);
    float* dinv   = (float*)carve((size_t)N * 4);
    int2*  rec    = (int2*)carve((size_t)E * 8);
    float* gbuf   = (float*)carve((size_t)G * DHID * 4);
    float* Wt     = (float*)carve((size_t)3 * 128 * 128 * 4);
    float* gi     = (float*)carve((size_t)3 * G * DHID * 4);
    unsigned short* A = (unsigned short*)carve((size_t)N * DHID * 2);   // bf16
    size_t matB = (size_t)N * DHID * sizeof(float);
    float* B;
    if (ws_size >= used + matB) {
        B = (float*)carve(matB);
    } else {
        B = (float*)d_in[0];   // harness restores inputs before every launch
    }

    dim3 blk(256);
    int nb_n  = (N + 255) / 256;
    int nb_e  = (E + 255) / 256;
    int nb_g  = (N + 31) / 32;
    int nb_ag = (N + 3) / 4;

    // ---- CSR build ----
    zero_counts<<<nb_n, blk, 0, stream>>>(cnt, N);
    cnt_accum<<<nb_e, blk, 0, stream>>>(dst, cnt, E);
    dinv_from_cnt<<<nb_n, blk, 0, stream>>>(cnt, dinv, N);
    scan_block<<<nb_n, blk, 0, stream>>>(cnt, off, bsum, N);
    scan_bsums<<<1, dim3(512), 0, stream>>>(bsum, nb_n);
    add_offsets<<<nb_n, blk, 0, stream>>>(off, bsum, cursor, N, E);
    fill_edges<<<nb_e, blk, 0, stream>>>(src, dst, dinv, cursor, rec, E);

    // ---- layer 1 ----
    gemm128<<<nb_g, blk, 0, stream>>>(x, W1, A, N, 0);
    aggregate<<<nb_ag, blk, 0, stream>>>(A, dinv, off, rec, b1, B, N);

    // ---- layer 2 ----
    gemm128<<<nb_g, blk, 0, stream>>>(B, W2, A, N, 1);
    aggregate<<<nb_ag, blk, 0, stream>>>(A, dinv, off, rec, b2, B, N);

    // ---- head ----
    pool_mean<<<G, blk, 0, stream>>>(B, batch, gbuf, N, G);
    transpose_wih<<<(3 * 128 * 128 + 255) / 256, blk, 0, stream>>>(W_ih, Wt);
    head_gemm<<<dim3((G + 31) / 32, 3), blk, 0, stream>>>(gbuf, Wt, gi, G);
    gate_ln_head<<<G, dim3(128), 0, stream>>>(gi, b_ih, b_hh, W_lin, b_lin, out, G);
}

// Round 5
// 469.623 us; speedup vs baseline: 6.5835x; 1.1966x over previous
//
#include <hip/hip_runtime.h>
#include <hip/hip_bf16.h>
#include <math.h>

#define DHID 128

typedef __attribute__((ext_vector_type(8))) short bf16x8;
typedef __attribute__((ext_vector_type(4))) float f32x4;

__device__ __forceinline__ int atomAddI(int* p, int v) {
    return __hip_atomic_fetch_add(p, v, __ATOMIC_RELAXED, __HIP_MEMORY_SCOPE_AGENT);
}
__device__ __forceinline__ float bf_lo(unsigned u) { return __uint_as_float(u << 16); }
__device__ __forceinline__ float bf_hi(unsigned u) { return __uint_as_float(u & 0xffff0000u); }
__device__ __forceinline__ float bf_us(unsigned short u) { return __uint_as_float((unsigned)u << 16); }
__device__ __forceinline__ unsigned short bf16_1(float f) {
    unsigned u = __float_as_uint(f);
    u += 0x7fffu + ((u >> 16) & 1u);   // RNE
    return (unsigned short)(u >> 16);
}
__device__ __forceinline__ unsigned pack_bf16x2(float a, float b) {
    unsigned ua = __float_as_uint(a);
    unsigned ub = __float_as_uint(b);
    ua = (ua + 0x7fffu + ((ua >> 16) & 1u)) >> 16;
    ub = (ub + 0x7fffu + ((ub >> 16) & 1u)) & 0xffff0000u;
    return ua | ub;
}

// ---------------- CSR build ----------------
__global__ void zero_counts(int* cnt, int N) {
    int i = blockIdx.x * 256 + threadIdx.x;
    if (i < N) cnt[i] = 0;
}

__global__ void cnt_accum(const int* __restrict__ dst, int* __restrict__ cnt, int E) {
    int e = blockIdx.x * 256 + threadIdx.x;
    if (e < E) atomAddI(&cnt[dst[e]], 1);
}

__global__ void dinv_from_cnt(const int* __restrict__ cnt, float* __restrict__ dinv, int N) {
    int i = blockIdx.x * 256 + threadIdx.x;
    if (i < N) dinv[i] = rsqrtf((float)cnt[i] + 1.0f);
}

__global__ __launch_bounds__(256) void scan_block(const int* __restrict__ cnt,
                                                  int* __restrict__ off,
                                                  int* __restrict__ bsum, int N) {
    __shared__ int sh[256];
    int t = threadIdx.x;
    int i = blockIdx.x * 256 + t;
    int v = (i < N) ? cnt[i] : 0;
    sh[t] = v;
    __syncthreads();
#pragma unroll
    for (int o = 1; o < 256; o <<= 1) {
        int x = (t >= o) ? sh[t - o] : 0;
        __syncthreads();
        sh[t] += x;
        __syncthreads();
    }
    if (i < N) off[i] = sh[t] - v;
    if (t == 255) bsum[blockIdx.x] = sh[255];
}

__global__ __launch_bounds__(512) void scan_bsums(int* bsum, int nb) {
    __shared__ int sh[512];
    int t = threadIdx.x;
    int carry = 0;
    for (int base = 0; base < nb; base += 512) {
        int idx = base + t;
        int v = (idx < nb) ? bsum[idx] : 0;
        sh[t] = v;
        __syncthreads();
#pragma unroll
        for (int o = 1; o < 512; o <<= 1) {
            int x = (t >= o) ? sh[t - o] : 0;
            __syncthreads();
            sh[t] += x;
            __syncthreads();
        }
        if (idx < nb) bsum[idx] = sh[t] - v + carry;
        carry += sh[511];
        __syncthreads();
    }
}

__global__ void add_offsets(int* __restrict__ off, const int* __restrict__ bsum,
                            int* __restrict__ cursor, int N, int E) {
    int i = blockIdx.x * 256 + threadIdx.x;
    if (i < N) {
        int o = off[i] + bsum[i >> 8];
        off[i] = o;
        cursor[i] = o;
    }
    if (i == 0) off[N] = E;
}

// one fused 8B record per edge: {src, norm-bits}
__global__ void fill_edges(const int* __restrict__ src, const int* __restrict__ dst,
                           const float* __restrict__ dinv, int* __restrict__ cursor,
                           int2* __restrict__ rec, int E) {
    int e = blockIdx.x * 256 + threadIdx.x;
    if (e >= E) return;
    int s = src[e], d = dst[e];
    int pos = atomAddI(&cursor[d], 1);
    rec[pos] = make_int2(s, __float_as_int(dinv[s] * dinv[d]));
}

// ---------------- weight prep: bf16 convert (+transpose for W1/W2) ----------------
// Wt[n][k] = bf16(W[k][n]) for the node GEMMs; W_ih used as-is ([j][k] == B-layout).
__global__ void prep_weights(const float* __restrict__ W1, const float* __restrict__ W2,
                             const float* __restrict__ Wih,
                             unsigned short* __restrict__ Wt1,
                             unsigned short* __restrict__ Wt2,
                             unsigned short* __restrict__ Wihb) {
    int idx = blockIdx.x * 256 + threadIdx.x;
    if (idx < 16384) {
        int k = idx >> 7, n = idx & 127;
        Wt1[n * 128 + k] = bf16_1(W1[idx]);
    } else if (idx < 32768) {
        int j = idx - 16384;
        int k = j >> 7, n = j & 127;
        Wt2[n * 128 + k] = bf16_1(W2[j]);
    } else if (idx < 32768 + 49152) {
        int j = idx - 32768;
        Wihb[j] = bf16_1(Wih[j]);
    }
}

// ---------------- MFMA GEMM: Y_bf16[rows,128] = X[rows,128] @ Wt^T ----------------
// Wt is bf16 [n][k] (n-major). X fp32 or bf16 per flag. 64 rows/block, 4 waves,
// each wave: 16 rows x 128 cols via 4 K-chunks x 8 col-tiles of 16x16x32 MFMA.
// LDS rows padded to 136 bf16 -> 2-way bank aliasing only (free).
__global__ __launch_bounds__(256) void gemm_mfma(const void* __restrict__ Xv,
                                                 const unsigned short* __restrict__ Wt,
                                                 unsigned short* __restrict__ Y,
                                                 int N, int x_is_bf16,
                                                 int wstride, int ystride) {
    __shared__ unsigned short Xs[64 * 136];
    __shared__ unsigned short Ws[128 * 136];
    const int tid = threadIdx.x;
    const unsigned short* Wg = Wt + (size_t)blockIdx.y * wstride;
    unsigned short* Yg = Y + (size_t)blockIdx.y * ystride;

    {
        const uint4* W4 = (const uint4*)Wg;   // 2048 uint4
#pragma unroll
        for (int i = 0; i < 8; i++) {
            int idx = tid + i * 256;
            int r = idx >> 4, c8 = idx & 15;
            *(uint4*)&Ws[r * 136 + c8 * 8] = W4[idx];
        }
    }
    const int row0 = blockIdx.x * 64;
    if (x_is_bf16) {
        const uint4* X4 = (const uint4*)Xv;   // 16 uint4 per row
#pragma unroll
        for (int i = 0; i < 4; i++) {
            int idx = tid + i * 256;
            int r = idx >> 4, c8 = idx & 15;
            uint4 v = make_uint4(0u, 0u, 0u, 0u);
            if (row0 + r < N) v = X4[(size_t)(row0 + r) * 16 + c8];
            *(uint4*)&Xs[r * 136 + c8 * 8] = v;
        }
    } else {
        const float4* X4 = (const float4*)Xv; // 32 float4 per row
#pragma unroll
        for (int i = 0; i < 8; i++) {
            int idx = tid + i * 256;
            int r = idx >> 5, c4 = idx & 31;
            float4 v = make_float4(0.f, 0.f, 0.f, 0.f);
            if (row0 + r < N) v = X4[(size_t)(row0 + r) * 32 + c4];
            uint2 pk = make_uint2(pack_bf16x2(v.x, v.y), pack_bf16x2(v.z, v.w));
            *(uint2*)&Xs[r * 136 + c4 * 4] = pk;
        }
    }
    __syncthreads();

    const int lane = tid & 63;
    const int wv = tid >> 6;
    const int m = lane & 15, quad = lane >> 4;
    const int wrow = wv * 16;

    f32x4 acc[8];
#pragma unroll
    for (int i = 0; i < 8; i++) acc[i] = (f32x4){0.f, 0.f, 0.f, 0.f};

#pragma unroll
    for (int kc = 0; kc < 4; kc++) {
        bf16x8 a = *(const bf16x8*)&Xs[(wrow + m) * 136 + kc * 32 + quad * 8];
#pragma unroll
        for (int nt = 0; nt < 8; nt++) {
            bf16x8 b = *(const bf16x8*)&Ws[(nt * 16 + m) * 136 + kc * 32 + quad * 8];
            acc[nt] = __builtin_amdgcn_mfma_f32_16x16x32_bf16(a, b, acc[nt], 0, 0, 0);
        }
    }

#pragma unroll
    for (int r = 0; r < 4; r++) {
        int row = row0 + wrow + quad * 4 + r;
        if (row < N) {
#pragma unroll
            for (int nt = 0; nt < 8; nt++) {
                Yg[(size_t)row * DHID + nt * 16 + m] = bf16_1(acc[nt][r]);
            }
        }
    }
}

// ---------------- CSR aggregate: bf16 gathers, fp32 accumulate ----------------
// mode 0: fp32 output; mode 1: relu + bf16 output (feeds next GEMM directly)
__global__ __launch_bounds__(256) void aggregate(const unsigned short* __restrict__ A,
                                                 const float* __restrict__ dinv,
                                                 const int* __restrict__ off,
                                                 const int2* __restrict__ rec,
                                                 const float* __restrict__ bias,
                                                 void* __restrict__ Bout, int N, int mode) {
    int node = blockIdx.x * 4 + (threadIdx.x >> 6);
    if (node >= N) return;
    int lane = threadIdx.x & 63;
    int half = lane >> 5;
    int l32  = lane & 31;
    float4 acc = make_float4(0.f, 0.f, 0.f, 0.f);
    if (half == 0) {
        float di = dinv[node];
        float s = di * di;
        uint2 v = ((const uint2*)(A + (size_t)node * DHID))[l32];
        float4 bb = ((const float4*)bias)[l32];
        acc.x = bf_lo(v.x) * s + bb.x;
        acc.y = bf_hi(v.x) * s + bb.y;
        acc.z = bf_lo(v.y) * s + bb.z;
        acc.w = bf_hi(v.y) * s + bb.w;
    }
    int j = off[node] + half;
    int jend = off[node + 1];
    for (; j + 2 < jend; j += 4) {
        int2 r0 = rec[j];
        int2 r1 = rec[j + 2];
        uint2 v0 = ((const uint2*)(A + (size_t)r0.x * DHID))[l32];
        uint2 v1 = ((const uint2*)(A + (size_t)r1.x * DHID))[l32];
        float w0 = __int_as_float(r0.y);
        float w1 = __int_as_float(r1.y);
        acc.x += bf_lo(v0.x) * w0 + bf_lo(v1.x) * w1;
        acc.y += bf_hi(v0.x) * w0 + bf_hi(v1.x) * w1;
        acc.z += bf_lo(v0.y) * w0 + bf_lo(v1.y) * w1;
        acc.w += bf_hi(v0.y) * w0 + bf_hi(v1.y) * w1;
    }
    if (j < jend) {
        int2 r = rec[j];
        uint2 v = ((const uint2*)(A + (size_t)r.x * DHID))[l32];
        float w = __int_as_float(r.y);
        acc.x += bf_lo(v.x) * w;
        acc.y += bf_hi(v.x) * w;
        acc.z += bf_lo(v.y) * w;
        acc.w += bf_hi(v.y) * w;
    }
    acc.x += __shfl_xor(acc.x, 32);
    acc.y += __shfl_xor(acc.y, 32);
    acc.z += __shfl_xor(acc.z, 32);
    acc.w += __shfl_xor(acc.w, 32);
    if (half == 0) {
        if (mode == 1) {
            float ax = fmaxf(acc.x, 0.f), ay = fmaxf(acc.y, 0.f);
            float az = fmaxf(acc.z, 0.f), aw = fmaxf(acc.w, 0.f);
            uint2 pk = make_uint2(pack_bf16x2(ax, ay), pack_bf16x2(az, aw));
            ((uint2*)((unsigned short*)Bout + (size_t)node * DHID))[l32] = pk;
        } else {
            ((float4*)((float*)Bout + (size_t)node * DHID))[l32] = acc;
        }
    }
}

// ---------------- pool: per-graph mean ----------------
__global__ __launch_bounds__(256) void pool_mean(const float* __restrict__ B,
                                                 const int* __restrict__ batch,
                                                 float* __restrict__ g, int N, int G) {
    __shared__ int se[2];
    __shared__ float red[128];
    const int t = threadIdx.x;
    const int gr = blockIdx.x;
    if (t < 2) {
        int target = gr + t, lo = 0, hi = N;
        while (lo < hi) {
            int mid = (lo + hi) >> 1;
            if (batch[mid] < target) lo = mid + 1; else hi = mid;
        }
        se[t] = lo;
    }
    __syncthreads();
    const int s = se[0], e = se[1];
    const int col = t & 127, rh = t >> 7;
    float sum = 0.f;
    for (int r = s + rh; r < e; r += 2) sum += B[(size_t)r * DHID + col];
    if (rh == 1) red[col] = sum;
    __syncthreads();
    if (rh == 0) {
        float tot = sum + red[col];
        g[(size_t)gr * DHID + col] = tot / fmaxf((float)(e - s), 1.0f);
    }
}

// ---------------- gates + relu + layernorm + linear ----------------
__global__ __launch_bounds__(128) void gate_ln_head(const unsigned short* __restrict__ gi,
                                                    const float* __restrict__ b_ih,
                                                    const float* __restrict__ b_hh,
                                                    const float* __restrict__ W_lin,
                                                    const float* __restrict__ b_lin,
                                                    float* __restrict__ out, int G) {
    __shared__ float red[2];
    const int t = threadIdx.x;
    const int g = blockIdx.x;

    float d0 = bf_us(gi[(size_t)g * DHID + t]);
    float d1 = bf_us(gi[(size_t)(G + g) * DHID + t]);
    float d2 = bf_us(gi[(size_t)(2 * G + g) * DHID + t]);

    float rg = 1.f / (1.f + expf(-(d0 + b_ih[t] + b_hh[t])));
    float zg = 1.f / (1.f + expf(-(d1 + b_ih[128 + t] + b_hh[128 + t])));
    float ng = tanhf(d2 + b_ih[256 + t] + rg * b_hh[256 + t]);
    float y = fmaxf((1.f - zg) * ng, 0.f);

    auto blockSum = [&](float v) -> float {
#pragma unroll
        for (int o = 1; o < 64; o <<= 1) v += __shfl_xor(v, o);
        __syncthreads();
        if ((t & 63) == 0) red[t >> 6] = v;
        __syncthreads();
        return red[0] + red[1];
    };

    float mu = blockSum(y) * (1.f / 128.f);
    float dy = y - mu;
    float var = blockSum(dy * dy) * (1.f / 128.f);
    float yn = dy * rsqrtf(var + 1e-5f);
    float tot = blockSum(yn * W_lin[t]);
    if (t == 0) out[g] = tot + b_lin[0];
}

extern "C" void kernel_launch(void* const* d_in, const int* in_sizes, int n_in,
                              void* d_out, int out_size, void* d_ws, size_t ws_size,
                              hipStream_t stream) {
    const float* x     = (const float*)d_in[0];
    const int*   ei    = (const int*)d_in[1];
    const int*   batch = (const int*)d_in[2];
    const float* W1    = (const float*)d_in[3];
    const float* b1    = (const float*)d_in[4];
    const float* W2    = (const float*)d_in[5];
    const float* b2    = (const float*)d_in[6];
    const float* W_ih  = (const float*)d_in[7];
    // d_in[8] = W_hh unused (h0 == 0)
    const float* b_ih  = (const float*)d_in[9];
    const float* b_hh  = (const float*)d_in[10];
    const float* W_lin = (const float*)d_in[11];
    const float* b_lin = (const float*)d_in[12];
    float* out = (float*)d_out;

    const int N = in_sizes[0] / DHID;
    const int E = in_sizes[1] / 2;
    const int G = out_size;
    const int* src = ei;
    const int* dst = ei + E;

    auto align256 = [](size_t v) { return (v + 255) & ~(size_t)255; };
    char* p = (char*)d_ws;
    size_t used = 0;
    auto carve = [&](size_t bytes) -> char* {
        char* q = p + used;
        used += align256(bytes);
        return q;
    };

    int*   cnt    = (int*)carve((size_t)N * 4);
    int*   off    = (int*)carve(((size_t)N + 1) * 4);
    int*   cursor = (int*)carve((size_t)N * 4);
    int*   bsum   = (int*)carve(4096 * 4);
    float* dinv   = (float*)carve((size_t)N * 4);
    int2*  rec    = (int2*)carve((size_t)E * 8);
    float* gbuf   = (float*)carve((size_t)G * DHID * 4);
    unsigned short* Wt1  = (unsigned short*)carve((size_t)128 * 128 * 2);
    unsigned short* Wt2  = (unsigned short*)carve((size_t)128 * 128 * 2);
    unsigned short* Wihb = (unsigned short*)carve((size_t)3 * 128 * 128 * 2);
    unsigned short* gib  = (unsigned short*)carve((size_t)3 * G * DHID * 2);
    unsigned short* A    = (unsigned short*)carve((size_t)N * DHID * 2);   // bf16
    unsigned short* B1b  = (unsigned short*)carve((size_t)N * DHID * 2);   // bf16, relu'd
    size_t matB = (size_t)N * DHID * sizeof(float);
    float* B2f;
    if (ws_size >= used + matB) {
        B2f = (float*)carve(matB);
    } else {
        B2f = (float*)d_in[0];   // x fully consumed by gemm-1 before agg-2 writes
    }

    dim3 blk(256);
    int nb_n  = (N + 255) / 256;
    int nb_e  = (E + 255) / 256;
    int nb_g  = (N + 63) / 64;
    int nb_ag = (N + 3) / 4;

    // ---- CSR build ----
    zero_counts<<<nb_n, blk, 0, stream>>>(cnt, N);
    cnt_accum<<<nb_e, blk, 0, stream>>>(dst, cnt, E);
    dinv_from_cnt<<<nb_n, blk, 0, stream>>>(cnt, dinv, N);
    scan_block<<<nb_n, blk, 0, stream>>>(cnt, off, bsum, N);
    scan_bsums<<<1, dim3(512), 0, stream>>>(bsum, nb_n);
    add_offsets<<<nb_n, blk, 0, stream>>>(off, bsum, cursor, N, E);
    fill_edges<<<nb_e, blk, 0, stream>>>(src, dst, dinv, cursor, rec, E);

    // ---- weights -> bf16 ----
    prep_weights<<<(32768 + 49152 + 255) / 256, blk, 0, stream>>>(W1, W2, W_ih, Wt1, Wt2, Wihb);

    // ---- layer 1 ----
    gemm_mfma<<<dim3(nb_g, 1), blk, 0, stream>>>(x, Wt1, A, N, 0, 0, 0);
    aggregate<<<nb_ag, blk, 0, stream>>>(A, dinv, off, rec, b1, B1b, N, 1);

    // ---- layer 2 ----
    gemm_mfma<<<dim3(nb_g, 1), blk, 0, stream>>>(B1b, Wt2, A, N, 1, 0, 0);
    aggregate<<<nb_ag, blk, 0, stream>>>(A, dinv, off, rec, b2, B2f, N, 0);

    // ---- head ----
    pool_mean<<<G, blk, 0, stream>>>(B2f, batch, gbuf, N, G);
    gemm_mfma<<<dim3((G + 63) / 64, 3), blk, 0, stream>>>(gbuf, Wihb, gib, G, 0,
                                                          128 * 128, G * DHID);
    gate_ln_head<<<G, dim3(128), 0, stream>>>(gib, b_ih, b_hh, W_lin, b_lin, out, G);
}